// Round 1
// baseline (1226.793 us; speedup 1.0000x reference)
//
#include <hip/hip_runtime.h>

typedef unsigned short u16;
typedef _Float16 f16;
typedef _Float16 f16x4 __attribute__((ext_vector_type(4)));
typedef _Float16 f16x8 __attribute__((ext_vector_type(8)));
typedef float    f32x4 __attribute__((ext_vector_type(4)));

#define BATCH 8
#define SEQ   4096
#define EMB   512
#define NCOL  512   // H*d = 8*64

// ---------------------------------------------------------------------------
// Prepass (unchanged): 5 planes, transpose W (f32 [k=512][n=512]) into f16 [n][k]:
//   z=0 WQ-hi, 1 WQ-lo(x256), 2 WK-hi, 3 WK-lo(x256), 4 WV.
__global__ __launch_bounds__(256) void prep_w(
    const float* __restrict__ Wq, const float* __restrict__ Wk,
    const float* __restrict__ Wv, u16* __restrict__ out)
{
  __shared__ u16 tile[64][65];
  const int z = blockIdx.z;
  const float* in = (z < 2) ? Wq : (z < 4) ? Wk : Wv;
  const bool lo = (z == 1 || z == 3);
  u16* o = out + (size_t)z * EMB * NCOL;
  const int r0 = blockIdx.y * 64, c0 = blockIdx.x * 64;
  const int tx = threadIdx.x, ty = threadIdx.y;
#pragma unroll
  for (int i = 0; i < 16; ++i) {
    const int r = ty * 16 + i;
    const float x = in[(size_t)(r0 + r) * NCOL + (c0 + tx)];
    const f16 h = (f16)x;
    const f16 v = lo ? (f16)((x - (float)h) * 256.0f) : h;
    tile[r][tx] = __builtin_bit_cast(u16, v);
  }
  __syncthreads();
#pragma unroll
  for (int i = 0; i < 16; ++i) {
    const int rr = ty * 16 + i;
    o[(size_t)(c0 + rr) * EMB + (r0 + tx)] = tile[tx][rr];
  }
}

// ---------------------------------------------------------------------------
// Fused v2.
//   Block: 512 thr (8 waves), tile = 64 rows x 256 cols, K double-buffered (32/step).
//   Wave w owns 64 rows x 32 cols (rt=4, ct=2, 16x16x32 f16 MFMA); waves cover
//   DISTINCT col slices -> W B-frags load global->reg (L2-resident), no LDS W.
//   X staged to LDS as f16-split planes (qh,ql,kh,kl,v), pad stride 40 f16
//   (bank-spread), reg-path staging: loads issued one tile early, writes at top
//   of iteration, ONE __syncthreads per K-tile.
//   Softmax over d=64 spans wave pair (w, w^1): (max, sum) exchange via LDS.
#define PSTRIDE 40              // f16 elems per LDS row (32 data + 8 pad)
#define PLANE   (64*PSTRIDE)    // 2560 f16 = 5120 B
#define BUFSZ   (5*PLANE)       // 12800 f16 = 25600 B

__global__ __launch_bounds__(512, 4) void fused_attn(
    const float* __restrict__ Xq, const float* __restrict__ Xk,
    const float* __restrict__ Xv,
    const int* __restrict__ Qlen, const int* __restrict__ Vlen,
    const u16* __restrict__ Wt,   // 5 planes of [512 n][512 k] f16
    float* __restrict__ out)
{
  const int b  = blockIdx.z;
  const int s0 = blockIdx.x * 64;
  const int c0 = blockIdx.y * 256;
  const int qlen = Qlen[b];
  const int t = threadIdx.x;

  if (s0 >= qlen) {           // fully masked tile: write zeros (64 x 256)
    const f32x4 z4 = {0.f, 0.f, 0.f, 0.f};
#pragma unroll
    for (int it = 0; it < 8; ++it) {
      const int f4  = it * 512 + t;
      const int row = f4 >> 6;
      const int col = (f4 & 63) * 4;
      *(f32x4*)(out + (size_t)(b * SEQ + s0 + row) * NCOL + c0 + col) = z4;
    }
    return;
  }
  const int vlen = Vlen[b];
  const int vl = (vlen == 0) ? 64 : vlen;  // uniform -1e12 shift cancels in softmax

  __shared__ f16 smem[2 * BUFSZ] __attribute__((aligned(16)));

  const int w    = t >> 6;      // 0..7 = col-slice index
  const int lane = t & 63;
  const int quad = lane >> 4;
  const int l15  = lane & 15;

  // staging lane mapping: 512 lanes cover [64 rows][32 k] x 3 tensors, 4 f32 each
  const int    srow = t >> 3;            // 0..63
  const int    sk4  = (t & 7) * 4;       // 0..28
  const size_t xg   = (size_t)(b * SEQ + s0 + srow) * EMB + sk4;
  const int    swo  = srow * PSTRIDE + sk4;   // f16 elem offset within plane

  // W global bases (per-lane): col = c0 + w*32 + ct*16 + l15, k = kk + quad*8
  const size_t wb = (size_t)(c0 + w * 32 + l15) * EMB + quad * 8;
  const u16* Wqh_g = Wt                + wb;
  const u16* Wql_g = Wt + 1 * EMB*NCOL + wb;
  const u16* Wkh_g = Wt + 2 * EMB*NCOL + wb;
  const u16* Wkl_g = Wt + 3 * EMB*NCOL + wb;
  const u16* Wv_g  = Wt + 4 * EMB*NCOL + wb;

  // A-frag LDS base (f16 elems): row = rt*16 + l15, k = quad*8
  const int ao = l15 * PSTRIDE + quad * 8;

  f32x4 accQ[4][2], accQc[4][2], accK[4][2], accKc[4][2], accV[4][2];
#pragma unroll
  for (int rt = 0; rt < 4; ++rt)
#pragma unroll
    for (int ct = 0; ct < 2; ++ct) {
      const f32x4 z = {0.f, 0.f, 0.f, 0.f};
      accQ[rt][ct] = z; accQc[rt][ct] = z;
      accK[rt][ct] = z; accKc[rt][ct] = z;
      accV[rt][ct] = z;
    }

  f32x4 rq[2], rk[2], rv[2];   // in-flight staging registers (2 slots)

#define LOADX(SLOT, TT) do { \
    rq[SLOT] = *(const f32x4*)(Xq + xg + (TT) * 32); \
    rk[SLOT] = *(const f32x4*)(Xk + xg + (TT) * 32); \
    rv[SLOT] = *(const f32x4*)(Xv + xg + (TT) * 32); \
  } while (0)

#define STAGE(SLOT, BOFS) do { \
    f16* p_ = smem + (BOFS); \
    f16x4 qh_, ql_, kh_, kl_, vh_; \
    _Pragma("unroll") \
    for (int j = 0; j < 4; ++j) { \
      const float xq_ = rq[SLOT][j]; const f16 qhh_ = (f16)xq_; \
      qh_[j] = qhh_; ql_[j] = (f16)((xq_ - (float)qhh_) * 256.0f); \
      const float xk_ = rk[SLOT][j]; const f16 khh_ = (f16)xk_; \
      kh_[j] = khh_; kl_[j] = (f16)((xk_ - (float)khh_) * 256.0f); \
      vh_[j] = (f16)rv[SLOT][j]; \
    } \
    *(f16x4*)(p_ + 0 * PLANE + swo) = qh_; \
    *(f16x4*)(p_ + 1 * PLANE + swo) = ql_; \
    *(f16x4*)(p_ + 2 * PLANE + swo) = kh_; \
    *(f16x4*)(p_ + 3 * PLANE + swo) = kl_; \
    *(f16x4*)(p_ + 4 * PLANE + swo) = vh_; \
  } while (0)

#define COMPUTE(BOFS, KK) do { \
    const f16* p_ = smem + (BOFS); \
    const int kk_ = (KK); \
    f16x8 bqh_[2], bql_[2], bkh_[2], bkl_[2], bv_[2]; \
    _Pragma("unroll") \
    for (int ct = 0; ct < 2; ++ct) { \
      const size_t wo_ = (size_t)ct * 16 * EMB + kk_; \
      bqh_[ct] = *(const f16x8*)(Wqh_g + wo_); \
      bql_[ct] = *(const f16x8*)(Wql_g + wo_); \
      bkh_[ct] = *(const f16x8*)(Wkh_g + wo_); \
      bkl_[ct] = *(const f16x8*)(Wkl_g + wo_); \
      bv_ [ct] = *(const f16x8*)(Wv_g  + wo_); \
    } \
    _Pragma("unroll") \
    for (int rt = 0; rt < 4; ++rt) { \
      const int ao_ = ao + rt * 16 * PSTRIDE; \
      const f16x8 aqh_ = *(const f16x8*)(p_ + 0 * PLANE + ao_); \
      const f16x8 aql_ = *(const f16x8*)(p_ + 1 * PLANE + ao_); \
      const f16x8 akh_ = *(const f16x8*)(p_ + 2 * PLANE + ao_); \
      const f16x8 akl_ = *(const f16x8*)(p_ + 3 * PLANE + ao_); \
      const f16x8 av_  = *(const f16x8*)(p_ + 4 * PLANE + ao_); \
      _Pragma("unroll") \
      for (int ct = 0; ct < 2; ++ct) { \
        accQ [rt][ct] = __builtin_amdgcn_mfma_f32_16x16x32_f16(aqh_, bqh_[ct], accQ [rt][ct], 0, 0, 0); \
        accQc[rt][ct] = __builtin_amdgcn_mfma_f32_16x16x32_f16(aqh_, bql_[ct], accQc[rt][ct], 0, 0, 0); \
        accQc[rt][ct] = __builtin_amdgcn_mfma_f32_16x16x32_f16(aql_, bqh_[ct], accQc[rt][ct], 0, 0, 0); \
        accK [rt][ct] = __builtin_amdgcn_mfma_f32_16x16x32_f16(akh_, bkh_[ct], accK [rt][ct], 0, 0, 0); \
        accKc[rt][ct] = __builtin_amdgcn_mfma_f32_16x16x32_f16(akh_, bkl_[ct], accKc[rt][ct], 0, 0, 0); \
        accKc[rt][ct] = __builtin_amdgcn_mfma_f32_16x16x32_f16(akl_, bkh_[ct], accKc[rt][ct], 0, 0, 0); \
        accV [rt][ct] = __builtin_amdgcn_mfma_f32_16x16x32_f16(av_,  bv_[ct],  accV [rt][ct], 0, 0, 0); \
      } \
    } \
  } while (0)

  // Prologue: data 0,1 in flight; stage data 0 into buf0.
  LOADX(0, 0);
  LOADX(1, 1);
  STAGE(0, 0);
  __syncthreads();

  // 16 K-tiles of 32; writes-at-top + single barrier per tile.
#pragma unroll 1
  for (int tt = 0; tt < 16; tt += 2) {
    STAGE(1, BUFSZ);                    // data tt+1 -> buf1
    if (tt < 14) LOADX(0, tt + 2);
    COMPUTE(0, tt * 32);                // data tt from buf0
    __syncthreads();
    if (tt < 14) STAGE(0, 0);           // data tt+2 -> buf0
    if (tt < 13) LOADX(1, tt + 3);
    COMPUTE(BUFSZ, (tt + 1) * 32);      // data tt+1 from buf1
    __syncthreads();
  }

#undef LOADX
#undef STAGE
#undef COMPUTE

  // -------------------------------------------------------------------------
  // Epilogue. Wave covers cols [w*32, w*32+32) of head (w>>1); softmax over
  // d=64 combines with partner wave w^1 via (max, sum) LDS exchange.
  const float scale = 0.125f;     // 1/sqrt(64)
  const float rs    = 1.0f / 256.0f;
  float* smf = (float*)smem;      // [8 waves][64 rows][2] = 4 KB (buf0 region; buf1 idle)

  float eA[4][2][4];              // exp(a - m_local), [rt][ct][r]
  float lm[4][4], lsum[4][4];     // local max / local sum per (rt, r)

#pragma unroll
  for (int rt = 0; rt < 4; ++rt) {
#pragma unroll
    for (int r = 0; r < 4; ++r) {
      float a[2]; bool msk[2];
      float mx = -3.0e38f;
#pragma unroll
      for (int ct = 0; ct < 2; ++ct) {
        const float q = accQ[rt][ct][r] + accQc[rt][ct][r] * rs;
        const float k = accK[rt][ct][r] + accKc[rt][ct][r] * rs;
        a[ct] = q * k * scale;
        msk[ct] = ((w & 1) * 32 + ct * 16 + l15) < vl;
        if (msk[ct]) mx = fmaxf(mx, a[ct]);
      }
#pragma unroll
      for (int off = 1; off < 16; off <<= 1) mx = fmaxf(mx, __shfl_xor(mx, off));
      float sum = 0.f;
#pragma unroll
      for (int ct = 0; ct < 2; ++ct) {
        const float e = msk[ct] ? __expf(a[ct] - mx) : 0.0f;
        eA[rt][ct][r] = e;
        sum += e;
      }
#pragma unroll
      for (int off = 1; off < 16; off <<= 1) sum += __shfl_xor(sum, off);
      lm[rt][r] = mx; lsum[rt][r] = sum;
      const int row = rt * 16 + quad * 4 + r;
      if (l15 == 0) {
        smf[(w * 64 + row) * 2 + 0] = mx;
        smf[(w * 64 + row) * 2 + 1] = sum;
      }
    }
  }
  __syncthreads();

#pragma unroll
  for (int rt = 0; rt < 4; ++rt) {
#pragma unroll
    for (int r = 0; r < 4; ++r) {
      const int row = rt * 16 + quad * 4 + r;
      const int s   = s0 + row;
      const float pm = smf[((w ^ 1) * 64 + row) * 2 + 0];
      const float ps = smf[((w ^ 1) * 64 + row) * 2 + 1];
      const float m  = lm[rt][r];
      const float M  = fmaxf(m, pm);
      const float S  = lsum[rt][r] * __expf(m - M) + ps * __expf(pm - M);
      const float qm = (s < qlen) ? 1.0f : 0.0f;
      const float f  = __expf(m - M) * qm / S;
      const size_t ob = (size_t)(b * SEQ + s) * NCOL + c0 + w * 32 + l15;
      out[ob]      = eA[rt][0][r] * f * accV[rt][0][r];
      out[ob + 16] = eA[rt][1][r] * f * accV[rt][1][r];
    }
  }
}

// ---------------------------------------------------------------------------
extern "C" void kernel_launch(void* const* d_in, const int* in_sizes, int n_in,
                              void* d_out, int out_size, void* d_ws, size_t ws_size,
                              hipStream_t stream) {
  const float* Xq   = (const float*)d_in[0];
  const float* Xk   = (const float*)d_in[1];
  const float* Xv   = (const float*)d_in[2];
  const int*   Qlen = (const int*)d_in[3];
  const int*   Vlen = (const int*)d_in[4];
  const float* Wq   = (const float*)d_in[5];
  const float* Wk   = (const float*)d_in[6];
  const float* Wv   = (const float*)d_in[7];
  u16*   Wt  = (u16*)d_ws;              // 5 * 512*512 * 2B = 2.5 MB
  float* out = (float*)d_out;

  dim3 pg(8, 8, 5), pb(64, 4, 1);
  prep_w<<<pg, pb, 0, stream>>>(Wq, Wk, Wv, Wt);

  dim3 g(SEQ / 64, NCOL / 256, BATCH), blk(512, 1, 1);
  fused_attn<<<g, blk, 0, stream>>>(Xq, Xk, Xv, Qlen, Vlen, Wt, out);
}

// Round 2
// 378.808 us; speedup vs baseline: 3.2386x; 3.2386x over previous
//
#include <hip/hip_runtime.h>

typedef unsigned short u16;
typedef _Float16 f16;
typedef _Float16 f16x4 __attribute__((ext_vector_type(4)));
typedef _Float16 f16x8 __attribute__((ext_vector_type(8)));
typedef float    f32x4 __attribute__((ext_vector_type(4)));

#define BATCH 8
#define SEQ   4096
#define EMB   512
#define NCOL  512   // H*d = 8*64

// ---------------------------------------------------------------------------
// Prepass (unchanged): 5 planes, transpose W (f32 [k=512][n=512]) into f16 [n][k]:
//   z=0 WQ-hi, 1 WQ-lo(x256), 2 WK-hi, 3 WK-lo(x256), 4 WV.
__global__ __launch_bounds__(256) void prep_w(
    const float* __restrict__ Wq, const float* __restrict__ Wk,
    const float* __restrict__ Wv, u16* __restrict__ out)
{
  __shared__ u16 tile[64][65];
  const int z = blockIdx.z;
  const float* in = (z < 2) ? Wq : (z < 4) ? Wk : Wv;
  const bool lo = (z == 1 || z == 3);
  u16* o = out + (size_t)z * EMB * NCOL;
  const int r0 = blockIdx.y * 64, c0 = blockIdx.x * 64;
  const int tx = threadIdx.x, ty = threadIdx.y;
#pragma unroll
  for (int i = 0; i < 16; ++i) {
    const int r = ty * 16 + i;
    const float x = in[(size_t)(r0 + r) * NCOL + (c0 + tx)];
    const f16 h = (f16)x;
    const f16 v = lo ? (f16)((x - (float)h) * 256.0f) : h;
    tile[r][tx] = __builtin_bit_cast(u16, v);
  }
  __syncthreads();
#pragma unroll
  for (int i = 0; i < 16; ++i) {
    const int rr = ty * 16 + i;
    o[(size_t)(c0 + rr) * EMB + (r0 + tx)] = tile[tx][rr];
  }
}

// ---------------------------------------------------------------------------
// Fused v3 = v2 structure with the spill fixed.
//   Block: 512 thr (8 waves), tile = 64 rows x 256 cols, K double-buffered (32/step).
//   Wave w owns 64 rows x 32 cols (rt=4, ct=2); waves cover DISTINCT col slices
//   -> W B-frags load global->reg (L2-resident), no LDS for W.
//   X staged to LDS as f16-split planes (qh,ql,kh,kl,v), pad stride 40 f16.
//   Single staging reg slot, ONE __syncthreads per K-step:
//     LOADX(t+1) -> COMPUTE(t) -> STAGE(t+1) -> barrier.
//   launch_bounds (512,2): 256-reg budget, 2 blocks/CU.
#define PSTRIDE 40              // f16 elems per LDS row (32 data + 8 pad)
#define PLANE   (64*PSTRIDE)    // 2560 f16 = 5120 B
#define BUFSZ   (5*PLANE)       // 12800 f16 = 25600 B

__global__ __launch_bounds__(512, 2) void fused_attn(
    const float* __restrict__ Xq, const float* __restrict__ Xk,
    const float* __restrict__ Xv,
    const int* __restrict__ Qlen, const int* __restrict__ Vlen,
    const u16* __restrict__ Wt,   // 5 planes of [512 n][512 k] f16
    float* __restrict__ out)
{
  const int b  = blockIdx.z;
  const int s0 = blockIdx.x * 64;
  const int c0 = blockIdx.y * 256;
  const int qlen = Qlen[b];
  const int t = threadIdx.x;

  if (s0 >= qlen) {           // fully masked tile: write zeros (64 x 256)
    const f32x4 z4 = {0.f, 0.f, 0.f, 0.f};
#pragma unroll
    for (int it = 0; it < 8; ++it) {
      const int f4  = it * 512 + t;
      const int row = f4 >> 6;
      const int col = (f4 & 63) * 4;
      *(f32x4*)(out + (size_t)(b * SEQ + s0 + row) * NCOL + c0 + col) = z4;
    }
    return;
  }
  const int vlen = Vlen[b];
  const int vl = (vlen == 0) ? 64 : vlen;  // uniform -1e12 shift cancels in softmax

  __shared__ f16 smem[2 * BUFSZ] __attribute__((aligned(16)));

  const int w    = t >> 6;      // 0..7 = col-slice index
  const int lane = t & 63;
  const int quad = lane >> 4;
  const int l15  = lane & 15;

  // staging lane mapping: 512 lanes cover [64 rows][32 k] x 3 tensors, 4 f32 each
  const int    srow = t >> 3;            // 0..63
  const int    sk4  = (t & 7) * 4;       // 0..28
  const size_t xg   = (size_t)(b * SEQ + s0 + srow) * EMB + sk4;
  const int    swo  = srow * PSTRIDE + sk4;   // f16 elem offset within plane

  // W global bases (per-lane): col = c0 + w*32 + ct*16 + l15, k = kk + quad*8
  const size_t wb = (size_t)(c0 + w * 32 + l15) * EMB + quad * 8;
  const u16* Wqh_g = Wt                + wb;
  const u16* Wql_g = Wt + 1 * EMB*NCOL + wb;
  const u16* Wkh_g = Wt + 2 * EMB*NCOL + wb;
  const u16* Wkl_g = Wt + 3 * EMB*NCOL + wb;
  const u16* Wv_g  = Wt + 4 * EMB*NCOL + wb;

  // A-frag LDS base (f16 elems): row = rt*16 + l15, k = quad*8
  const int ao = l15 * PSTRIDE + quad * 8;

  f32x4 accQ[4][2], accQc[4][2], accK[4][2], accKc[4][2], accV[4][2];
#pragma unroll
  for (int rt = 0; rt < 4; ++rt)
#pragma unroll
    for (int ct = 0; ct < 2; ++ct) {
      const f32x4 z = {0.f, 0.f, 0.f, 0.f};
      accQ[rt][ct] = z; accQc[rt][ct] = z;
      accK[rt][ct] = z; accKc[rt][ct] = z;
      accV[rt][ct] = z;
    }

  f32x4 rq, rk, rv;   // single in-flight staging slot

#define LOADX(TT) do { \
    rq = *(const f32x4*)(Xq + xg + (TT) * 32); \
    rk = *(const f32x4*)(Xk + xg + (TT) * 32); \
    rv = *(const f32x4*)(Xv + xg + (TT) * 32); \
  } while (0)

#define STAGE(BOFS) do { \
    f16* p_ = smem + (BOFS); \
    f16x4 qh_, ql_, kh_, kl_, vh_; \
    _Pragma("unroll") \
    for (int j = 0; j < 4; ++j) { \
      const float xq_ = rq[j]; const f16 qhh_ = (f16)xq_; \
      qh_[j] = qhh_; ql_[j] = (f16)((xq_ - (float)qhh_) * 256.0f); \
      const float xk_ = rk[j]; const f16 khh_ = (f16)xk_; \
      kh_[j] = khh_; kl_[j] = (f16)((xk_ - (float)khh_) * 256.0f); \
      vh_[j] = (f16)rv[j]; \
    } \
    *(f16x4*)(p_ + 0 * PLANE + swo) = qh_; \
    *(f16x4*)(p_ + 1 * PLANE + swo) = ql_; \
    *(f16x4*)(p_ + 2 * PLANE + swo) = kh_; \
    *(f16x4*)(p_ + 3 * PLANE + swo) = kl_; \
    *(f16x4*)(p_ + 4 * PLANE + swo) = vh_; \
  } while (0)

#define COMPUTE(BOFS, KK) do { \
    const f16* p_ = smem + (BOFS); \
    const int kk_ = (KK); \
    f16x8 bqh_[2], bql_[2], bkh_[2], bkl_[2], bv_[2]; \
    _Pragma("unroll") \
    for (int ct = 0; ct < 2; ++ct) { \
      const size_t wo_ = (size_t)ct * 16 * EMB + kk_; \
      bqh_[ct] = *(const f16x8*)(Wqh_g + wo_); \
      bql_[ct] = *(const f16x8*)(Wql_g + wo_); \
      bkh_[ct] = *(const f16x8*)(Wkh_g + wo_); \
      bkl_[ct] = *(const f16x8*)(Wkl_g + wo_); \
      bv_ [ct] = *(const f16x8*)(Wv_g  + wo_); \
    } \
    _Pragma("unroll") \
    for (int rt = 0; rt < 4; ++rt) { \
      const int ao_ = ao + rt * 16 * PSTRIDE; \
      const f16x8 aqh_ = *(const f16x8*)(p_ + 0 * PLANE + ao_); \
      const f16x8 aql_ = *(const f16x8*)(p_ + 1 * PLANE + ao_); \
      const f16x8 akh_ = *(const f16x8*)(p_ + 2 * PLANE + ao_); \
      const f16x8 akl_ = *(const f16x8*)(p_ + 3 * PLANE + ao_); \
      const f16x8 av_  = *(const f16x8*)(p_ + 4 * PLANE + ao_); \
      _Pragma("unroll") \
      for (int ct = 0; ct < 2; ++ct) { \
        accQ [rt][ct] = __builtin_amdgcn_mfma_f32_16x16x32_f16(aqh_, bqh_[ct], accQ [rt][ct], 0, 0, 0); \
        accQc[rt][ct] = __builtin_amdgcn_mfma_f32_16x16x32_f16(aqh_, bql_[ct], accQc[rt][ct], 0, 0, 0); \
        accQc[rt][ct] = __builtin_amdgcn_mfma_f32_16x16x32_f16(aql_, bqh_[ct], accQc[rt][ct], 0, 0, 0); \
        accK [rt][ct] = __builtin_amdgcn_mfma_f32_16x16x32_f16(akh_, bkh_[ct], accK [rt][ct], 0, 0, 0); \
        accKc[rt][ct] = __builtin_amdgcn_mfma_f32_16x16x32_f16(akh_, bkl_[ct], accKc[rt][ct], 0, 0, 0); \
        accKc[rt][ct] = __builtin_amdgcn_mfma_f32_16x16x32_f16(akl_, bkh_[ct], accKc[rt][ct], 0, 0, 0); \
        accV [rt][ct] = __builtin_amdgcn_mfma_f32_16x16x32_f16(av_,  bv_[ct],  accV [rt][ct], 0, 0, 0); \
      } \
    } \
  } while (0)

  // Prologue: stage data 0 into buf0.
  LOADX(0);
  STAGE(0);
  __syncthreads();

  // 16 K-tiles of 32; one barrier per step; unroll x2 for buffer toggle.
#pragma unroll 1
  for (int tt = 0; tt < 16; tt += 2) {
    // even step: compute buf0, stage data tt+1 into buf1
    LOADX(tt + 1);
    COMPUTE(0, tt * 32);
    STAGE(BUFSZ);
    __syncthreads();
    // odd step: compute buf1, stage data tt+2 into buf0
    if (tt < 14) LOADX(tt + 2);
    COMPUTE(BUFSZ, (tt + 1) * 32);
    if (tt < 14) STAGE(0);
    __syncthreads();
  }

#undef LOADX
#undef STAGE
#undef COMPUTE

  // -------------------------------------------------------------------------
  // Epilogue. Wave covers cols [w*32, w*32+32) of head (w>>1); softmax over
  // d=64 combines with partner wave w^1 via (max, sum) LDS exchange.
  const float scale = 0.125f;     // 1/sqrt(64)
  const float rs    = 1.0f / 256.0f;
  float* smf = (float*)smem;      // [8 waves][64 rows][2] = 4 KB (buf0 region)

  float eA[4][2][4];              // exp(a - m_local), [rt][ct][r]
  float lm[4][4], lsum[4][4];     // local max / local sum per (rt, r)

#pragma unroll
  for (int rt = 0; rt < 4; ++rt) {
#pragma unroll
    for (int r = 0; r < 4; ++r) {
      float a[2]; bool msk[2];
      float mx = -3.0e38f;
#pragma unroll
      for (int ct = 0; ct < 2; ++ct) {
        const float q = accQ[rt][ct][r] + accQc[rt][ct][r] * rs;
        const float k = accK[rt][ct][r] + accKc[rt][ct][r] * rs;
        a[ct] = q * k * scale;
        msk[ct] = ((w & 1) * 32 + ct * 16 + l15) < vl;
        if (msk[ct]) mx = fmaxf(mx, a[ct]);
      }
#pragma unroll
      for (int off = 1; off < 16; off <<= 1) mx = fmaxf(mx, __shfl_xor(mx, off));
      float sum = 0.f;
#pragma unroll
      for (int ct = 0; ct < 2; ++ct) {
        const float e = msk[ct] ? __expf(a[ct] - mx) : 0.0f;
        eA[rt][ct][r] = e;
        sum += e;
      }
#pragma unroll
      for (int off = 1; off < 16; off <<= 1) sum += __shfl_xor(sum, off);
      lm[rt][r] = mx; lsum[rt][r] = sum;
      const int row = rt * 16 + quad * 4 + r;
      if (l15 == 0) {
        smf[(w * 64 + row) * 2 + 0] = mx;
        smf[(w * 64 + row) * 2 + 1] = sum;
      }
    }
  }
  __syncthreads();

#pragma unroll
  for (int rt = 0; rt < 4; ++rt) {
#pragma unroll
    for (int r = 0; r < 4; ++r) {
      const int row = rt * 16 + quad * 4 + r;
      const int s   = s0 + row;
      const float pm = smf[((w ^ 1) * 64 + row) * 2 + 0];
      const float ps = smf[((w ^ 1) * 64 + row) * 2 + 1];
      const float m  = lm[rt][r];
      const float M  = fmaxf(m, pm);
      const float S  = lsum[rt][r] * __expf(m - M) + ps * __expf(pm - M);
      const float qm = (s < qlen) ? 1.0f : 0.0f;
      const float f  = __expf(m - M) * qm / S;
      const size_t ob = (size_t)(b * SEQ + s) * NCOL + c0 + w * 32 + l15;
      out[ob]      = eA[rt][0][r] * f * accV[rt][0][r];
      out[ob + 16] = eA[rt][1][r] * f * accV[rt][1][r];
    }
  }
}

// ---------------------------------------------------------------------------
extern "C" void kernel_launch(void* const* d_in, const int* in_sizes, int n_in,
                              void* d_out, int out_size, void* d_ws, size_t ws_size,
                              hipStream_t stream) {
  const float* Xq   = (const float*)d_in[0];
  const float* Xk   = (const float*)d_in[1];
  const float* Xv   = (const float*)d_in[2];
  const int*   Qlen = (const int*)d_in[3];
  const int*   Vlen = (const int*)d_in[4];
  const float* Wq   = (const float*)d_in[5];
  const float* Wk   = (const float*)d_in[6];
  const float* Wv   = (const float*)d_in[7];
  u16*   Wt  = (u16*)d_ws;              // 5 * 512*512 * 2B = 2.5 MB
  float* out = (float*)d_out;

  dim3 pg(8, 8, 5), pb(64, 4, 1);
  prep_w<<<pg, pb, 0, stream>>>(Wq, Wk, Wv, Wt);

  dim3 g(SEQ / 64, NCOL / 256, BATCH), blk(512, 1, 1);
  fused_attn<<<g, blk, 0, stream>>>(Xq, Xk, Xv, Qlen, Vlen, Wt, out);
}

// Round 3
// 357.351 us; speedup vs baseline: 3.4330x; 1.0600x over previous
//
#include <hip/hip_runtime.h>

typedef unsigned short u16;
typedef _Float16 f16;
typedef _Float16 f16x4 __attribute__((ext_vector_type(4)));
typedef _Float16 f16x8 __attribute__((ext_vector_type(8)));
typedef float    f32x4 __attribute__((ext_vector_type(4)));

#define BATCH 8
#define SEQ   4096
#define EMB   512
#define NCOL  512   // H*d = 8*64

// ---------------------------------------------------------------------------
// Prepass: 5 planes, transpose W (f32 [k=512][n=512]) into f16 [n][k]:
//   z=0 WQ-hi, 1 WQ-lo4 = (x-hi)*16, 2 WK-hi, 3 WK-lo4, 4 WV.
// Recombine happens inside the MFMA accumulator:
//   w ~= wh + (wl4*2^-4)  with the 2^-4 folded into the A-side fragment.
__global__ __launch_bounds__(256) void prep_w(
    const float* __restrict__ Wq, const float* __restrict__ Wk,
    const float* __restrict__ Wv, u16* __restrict__ out)
{
  __shared__ u16 tile[64][65];
  const int z = blockIdx.z;
  const float* in = (z < 2) ? Wq : (z < 4) ? Wk : Wv;
  const bool lo = (z == 1 || z == 3);
  u16* o = out + (size_t)z * EMB * NCOL;
  const int r0 = blockIdx.y * 64, c0 = blockIdx.x * 64;
  const int tx = threadIdx.x, ty = threadIdx.y;
#pragma unroll
  for (int i = 0; i < 16; ++i) {
    const int r = ty * 16 + i;
    const float x = in[(size_t)(r0 + r) * NCOL + (c0 + tx)];
    const f16 h = (f16)x;
    const f16 v = lo ? (f16)((x - (float)h) * 16.0f) : h;
    tile[r][tx] = __builtin_bit_cast(u16, v);
  }
  __syncthreads();
#pragma unroll
  for (int i = 0; i < 16; ++i) {
    const int rr = ty * 16 + i;
    o[(size_t)(c0 + rr) * EMB + (r0 + tx)] = tile[tx][rr];
  }
}

// ---------------------------------------------------------------------------
// Fused v4: 3 accumulator sets (96 VGPR) via K-extension of the f16 split.
//   Block: 512 thr (8 waves), tile = 64 rows x 256 cols, K double-buffered.
//   Wave w owns 64 rows x 32 cols (rt=4, ct=2); W B-frags global->reg.
//   A-planes in LDS (qh, ql4, kh, kl4, v), XOR-swizzled 16B units.
//   q = qh*wh + (qh*2^-4)*wl4 + ql4*(wh*2^-4), all into ONE f32 acc.
#define PLANE 2048              // f16 per plane: 64 rows x 32
#define BUFSZ (5*PLANE)         // 10240 f16 = 20 KB

__global__ __launch_bounds__(512, 2) void fused_attn(
    const float* __restrict__ Xq, const float* __restrict__ Xk,
    const float* __restrict__ Xv,
    const int* __restrict__ Qlen, const int* __restrict__ Vlen,
    const u16* __restrict__ Wt,   // 5 planes of [512 n][512 k] f16
    float* __restrict__ out)
{
  const int b  = blockIdx.z;
  const int s0 = blockIdx.x * 64;
  const int c0 = blockIdx.y * 256;
  const int qlen = Qlen[b];
  const int t = threadIdx.x;

  if (s0 >= qlen) {           // fully masked tile: write zeros (64 x 256)
    const f32x4 z4 = {0.f, 0.f, 0.f, 0.f};
#pragma unroll
    for (int it = 0; it < 8; ++it) {
      const int f4  = it * 512 + t;
      const int row = f4 >> 6;
      const int col = (f4 & 63) * 4;
      *(f32x4*)(out + (size_t)(b * SEQ + s0 + row) * NCOL + c0 + col) = z4;
    }
    return;
  }
  const int vlen = Vlen[b];
  const int vl = (vlen == 0) ? 64 : vlen;  // uniform -1e12 shift cancels in softmax

  __shared__ f16 smem[2 * BUFSZ] __attribute__((aligned(16)));   // 40 KB

  const int w    = t >> 6;      // 0..7 = col-slice index
  const int lane = t & 63;
  const int quad = lane >> 4;
  const int l15  = lane & 15;

  // staging lane mapping: 512 lanes cover [64 rows][32 k], 4 f32 each
  const int    srow = t >> 3;            // 0..63
  const int    sj   = t & 7;             // 0..7 (4-float chunk)
  const size_t xg   = (size_t)(b * SEQ + s0 + srow) * EMB + sj * 4;
  // swizzled write offset: row*32 + (unit ^ ((row>>1)&3))*8 + (sj&1)*4
  const int    swo  = srow * 32 + (((sj >> 1) ^ ((srow >> 1) & 3)) * 8) + (sj & 1) * 4;

  // W global bases (per-lane): col = c0 + w*32 + ct*16 + l15, k = kk + quad*8
  const size_t wb = (size_t)(c0 + w * 32 + l15) * EMB + quad * 8;
  const u16* Wqh_g = Wt                + wb;
  const u16* Wql_g = Wt + 1 * EMB*NCOL + wb;
  const u16* Wkh_g = Wt + 2 * EMB*NCOL + wb;
  const u16* Wkl_g = Wt + 3 * EMB*NCOL + wb;
  const u16* Wv_g  = Wt + 4 * EMB*NCOL + wb;

  // A-frag LDS base (f16 elems), swizzle is rt-independent:
  const int swz = (l15 >> 1) & 3;
  const int ao  = l15 * 32 + ((quad ^ swz) * 8);

  f32x4 accQ[4][2], accK[4][2], accV[4][2];
#pragma unroll
  for (int rt = 0; rt < 4; ++rt)
#pragma unroll
    for (int ct = 0; ct < 2; ++ct) {
      const f32x4 z = {0.f, 0.f, 0.f, 0.f};
      accQ[rt][ct] = z; accK[rt][ct] = z; accV[rt][ct] = z;
    }

  f32x4 rq, rk, rv;   // single in-flight staging slot

#define LOADX(TT) do { \
    rq = *(const f32x4*)(Xq + xg + (TT) * 32); \
    rk = *(const f32x4*)(Xk + xg + (TT) * 32); \
    rv = *(const f32x4*)(Xv + xg + (TT) * 32); \
  } while (0)

#define STAGE(BOFS) do { \
    f16* p_ = smem + (BOFS); \
    f16x4 qh_, ql_, kh_, kl_, vh_; \
    _Pragma("unroll") \
    for (int j = 0; j < 4; ++j) { \
      const float xq_ = rq[j]; const f16 qhh_ = (f16)xq_; \
      qh_[j] = qhh_; ql_[j] = (f16)((xq_ - (float)qhh_) * 16.0f); \
      const float xk_ = rk[j]; const f16 khh_ = (f16)xk_; \
      kh_[j] = khh_; kl_[j] = (f16)((xk_ - (float)khh_) * 16.0f); \
      vh_[j] = (f16)rv[j]; \
    } \
    *(f16x4*)(p_ + 0 * PLANE + swo) = qh_; \
    *(f16x4*)(p_ + 1 * PLANE + swo) = ql_; \
    *(f16x4*)(p_ + 2 * PLANE + swo) = kh_; \
    *(f16x4*)(p_ + 3 * PLANE + swo) = kl_; \
    *(f16x4*)(p_ + 4 * PLANE + swo) = vh_; \
  } while (0)

#define COMPUTE(BOFS, KK) do { \
    const f16* p_ = smem + (BOFS); \
    const int kk_ = (KK); \
    /* hoist ALL B loads: in-order vmcnt lets Q-phase MFMAs cover K/V load latency */ \
    f16x8 bqh_[2], bql_[2], bkh_[2], bkl_[2], bv_[2]; \
    _Pragma("unroll") \
    for (int ct = 0; ct < 2; ++ct) { \
      const size_t wo_ = (size_t)ct * 16 * EMB + kk_; \
      bqh_[ct] = *(const f16x8*)(Wqh_g + wo_); \
      bql_[ct] = *(const f16x8*)(Wql_g + wo_); \
      bkh_[ct] = *(const f16x8*)(Wkh_g + wo_); \
      bkl_[ct] = *(const f16x8*)(Wkl_g + wo_); \
      bv_ [ct] = *(const f16x8*)(Wv_g  + wo_); \
    } \
    /* ---- Q phase ---- */ \
    { \
      f16x8 b4_[2]; \
      _Pragma("unroll") \
      for (int ct = 0; ct < 2; ++ct) \
        _Pragma("unroll") \
        for (int jj = 0; jj < 8; ++jj) b4_[ct][jj] = bqh_[ct][jj] * (f16)0.0625f; \
      _Pragma("unroll") \
      for (int rt = 0; rt < 4; ++rt) { \
        const int ao_ = ao + rt * 512; \
        const f16x8 ah_ = *(const f16x8*)(p_ + 0 * PLANE + ao_); \
        const f16x8 al_ = *(const f16x8*)(p_ + 1 * PLANE + ao_); \
        f16x8 a4_; \
        _Pragma("unroll") \
        for (int jj = 0; jj < 8; ++jj) a4_[jj] = ah_[jj] * (f16)0.0625f; \
        _Pragma("unroll") \
        for (int ct = 0; ct < 2; ++ct) { \
          accQ[rt][ct] = __builtin_amdgcn_mfma_f32_16x16x32_f16(ah_, bqh_[ct], accQ[rt][ct], 0, 0, 0); \
          accQ[rt][ct] = __builtin_amdgcn_mfma_f32_16x16x32_f16(a4_, bql_[ct], accQ[rt][ct], 0, 0, 0); \
          accQ[rt][ct] = __builtin_amdgcn_mfma_f32_16x16x32_f16(al_, b4_[ct],  accQ[rt][ct], 0, 0, 0); \
        } \
      } \
    } \
    /* ---- K phase ---- */ \
    { \
      f16x8 b4_[2]; \
      _Pragma("unroll") \
      for (int ct = 0; ct < 2; ++ct) \
        _Pragma("unroll") \
        for (int jj = 0; jj < 8; ++jj) b4_[ct][jj] = bkh_[ct][jj] * (f16)0.0625f; \
      _Pragma("unroll") \
      for (int rt = 0; rt < 4; ++rt) { \
        const int ao_ = ao + rt * 512; \
        const f16x8 ah_ = *(const f16x8*)(p_ + 2 * PLANE + ao_); \
        const f16x8 al_ = *(const f16x8*)(p_ + 3 * PLANE + ao_); \
        f16x8 a4_; \
        _Pragma("unroll") \
        for (int jj = 0; jj < 8; ++jj) a4_[jj] = ah_[jj] * (f16)0.0625f; \
        _Pragma("unroll") \
        for (int ct = 0; ct < 2; ++ct) { \
          accK[rt][ct] = __builtin_amdgcn_mfma_f32_16x16x32_f16(ah_, bkh_[ct], accK[rt][ct], 0, 0, 0); \
          accK[rt][ct] = __builtin_amdgcn_mfma_f32_16x16x32_f16(a4_, bkl_[ct], accK[rt][ct], 0, 0, 0); \
          accK[rt][ct] = __builtin_amdgcn_mfma_f32_16x16x32_f16(al_, b4_[ct],  accK[rt][ct], 0, 0, 0); \
        } \
      } \
    } \
    /* ---- V phase ---- */ \
    _Pragma("unroll") \
    for (int rt = 0; rt < 4; ++rt) { \
      const int ao_ = ao + rt * 512; \
      const f16x8 av_ = *(const f16x8*)(p_ + 4 * PLANE + ao_); \
      _Pragma("unroll") \
      for (int ct = 0; ct < 2; ++ct) \
        accV[rt][ct] = __builtin_amdgcn_mfma_f32_16x16x32_f16(av_, bv_[ct], accV[rt][ct], 0, 0, 0); \
    } \
  } while (0)

  // Prologue: stage data 0 into buf0.
  LOADX(0);
  STAGE(0);
  __syncthreads();

  // 16 K-tiles of 32; one barrier per step; unroll x2 for buffer toggle.
#pragma unroll 1
  for (int tt = 0; tt < 16; tt += 2) {
    // even step: compute buf0, stage data tt+1 into buf1
    LOADX(tt + 1);
    COMPUTE(0, tt * 32);
    STAGE(BUFSZ);
    __syncthreads();
    // odd step: compute buf1, stage data tt+2 into buf0
    if (tt < 14) LOADX(tt + 2);
    COMPUTE(BUFSZ, (tt + 1) * 32);
    if (tt < 14) STAGE(0);
    __syncthreads();
  }

#undef LOADX
#undef STAGE
#undef COMPUTE

  // -------------------------------------------------------------------------
  // Epilogue. Wave covers cols [w*32, w*32+32) of head (w>>1); softmax over
  // d=64 combines with partner wave w^1 via (max, sum) LDS exchange.
  const float scale = 0.125f;     // 1/sqrt(64)
  float* smf = (float*)smem;      // [8 waves][64 rows][2] = 4 KB (buf0 region)

  float eA[4][2][4];              // exp(a - m_local), [rt][ct][r]
  float lm[4][4], lsum[4][4];     // local max / local sum per (rt, r)

#pragma unroll
  for (int rt = 0; rt < 4; ++rt) {
#pragma unroll
    for (int r = 0; r < 4; ++r) {
      float a[2]; bool msk[2];
      float mx = -3.0e38f;
#pragma unroll
      for (int ct = 0; ct < 2; ++ct) {
        const float q = accQ[rt][ct][r];
        const float k = accK[rt][ct][r];
        a[ct] = q * k * scale;
        msk[ct] = ((w & 1) * 32 + ct * 16 + l15) < vl;
        if (msk[ct]) mx = fmaxf(mx, a[ct]);
      }
#pragma unroll
      for (int off = 1; off < 16; off <<= 1) mx = fmaxf(mx, __shfl_xor(mx, off));
      float sum = 0.f;
#pragma unroll
      for (int ct = 0; ct < 2; ++ct) {
        const float e = msk[ct] ? __expf(a[ct] - mx) : 0.0f;
        eA[rt][ct][r] = e;
        sum += e;
      }
#pragma unroll
      for (int off = 1; off < 16; off <<= 1) sum += __shfl_xor(sum, off);
      lm[rt][r] = mx; lsum[rt][r] = sum;
      const int row = rt * 16 + quad * 4 + r;
      if (l15 == 0) {
        smf[(w * 64 + row) * 2 + 0] = mx;
        smf[(w * 64 + row) * 2 + 1] = sum;
      }
    }
  }
  __syncthreads();

#pragma unroll
  for (int rt = 0; rt < 4; ++rt) {
#pragma unroll
    for (int r = 0; r < 4; ++r) {
      const int row = rt * 16 + quad * 4 + r;
      const int s   = s0 + row;
      const float pm = smf[((w ^ 1) * 64 + row) * 2 + 0];
      const float ps = smf[((w ^ 1) * 64 + row) * 2 + 1];
      const float m  = lm[rt][r];
      const float M  = fmaxf(m, pm);
      const float S  = lsum[rt][r] * __expf(m - M) + ps * __expf(pm - M);
      const float qm = (s < qlen) ? 1.0f : 0.0f;
      const float f  = __expf(m - M) * qm / S;
      const size_t ob = (size_t)(b * SEQ + s) * NCOL + c0 + w * 32 + l15;
      out[ob]      = eA[rt][0][r] * f * accV[rt][0][r];
      out[ob + 16] = eA[rt][1][r] * f * accV[rt][1][r];
    }
  }
}

// ---------------------------------------------------------------------------
extern "C" void kernel_launch(void* const* d_in, const int* in_sizes, int n_in,
                              void* d_out, int out_size, void* d_ws, size_t ws_size,
                              hipStream_t stream) {
  const float* Xq   = (const float*)d_in[0];
  const float* Xk   = (const float*)d_in[1];
  const float* Xv   = (const float*)d_in[2];
  const int*   Qlen = (const int*)d_in[3];
  const int*   Vlen = (const int*)d_in[4];
  const float* Wq   = (const float*)d_in[5];
  const float* Wk   = (const float*)d_in[6];
  const float* Wv   = (const float*)d_in[7];
  u16*   Wt  = (u16*)d_ws;              // 5 * 512*512 * 2B = 2.5 MB
  float* out = (float*)d_out;

  dim3 pg(8, 8, 5), pb(64, 4, 1);
  prep_w<<<pg, pb, 0, stream>>>(Wq, Wk, Wv, Wt);

  dim3 g(SEQ / 64, NCOL / 256, BATCH), blk(512, 1, 1);
  fused_attn<<<g, blk, 0, stream>>>(Xq, Xk, Xv, Qlen, Vlen, Wt, out);
}